// Round 5
// baseline (444.592 us; speedup 1.0000x reference)
//
#include <hip/hip_runtime.h>
#include <math.h>

#define B_   256
#define V_   6890
#define NJ_  24
#define NB_  10
#define NP_  207
#define NJR_ 43
#define V3_  20670   // V*3
#define NK_  217     // NB + NP
#define NJ3_ 129     // NJR*3
#define JOUT_ 33024  // B*NJR*3
#define NCH_ 16      // v-chunks for k_jst

// ws layout (floats)
#define JSTP_OFF 0        // 16 * 792 = 12672 partial Jst
#define CG_OFF   16384    // coefG: 217*256 = 55552
#define A_OFF    73728    // 256*24*12 = 73728
#define JP_OFF   147456   // joint partials: 4 * 33024 = 132096

// ---------------------------------------------------------------------------
// K0: partial Jst.  grid = 16 v-chunks; block 192 = 24 joints x 8 sub-lanes.
// sd/vtm read ONCE device-wide (all joints share one block's loads via L1).
// ---------------------------------------------------------------------------
__global__ __launch_bounds__(192) void k_jst(const float* __restrict__ JR,
                                             const float* __restrict__ vtm,
                                             const float* __restrict__ sd,
                                             float* __restrict__ JstP)
{
    const int c = blockIdx.x;
    const int tid = threadIdx.x;          // 0..191
    const int j = tid >> 3;               // 0..23
    const int s = tid & 7;                // 0..7
    const int v0 = c * 431;
    const int v1 = (v0 + 431 < V_) ? v0 + 431 : V_;

    float acc[33];
#pragma unroll
    for (int q = 0; q < 33; q++) acc[q] = 0.f;

    for (int v = v0 + s; v < v1; v += 8) {
        float jr = JR[(size_t)j * V_ + v];
        const float* tv = vtm + (size_t)v * 3;
        acc[0] += jr * tv[0];
        acc[1] += jr * tv[1];
        acc[2] += jr * tv[2];
#pragma unroll
        for (int k = 0; k < 10; k++) {
            const float* sp = sd + (size_t)k * V3_ + (size_t)v * 3;
            acc[3 + k*3 + 0] += jr * sp[0];
            acc[3 + k*3 + 1] += jr * sp[1];
            acc[3 + k*3 + 2] += jr * sp[2];
        }
    }
    // reduce across the 8 sub-lanes (aligned groups within a wave)
#pragma unroll
    for (int q = 0; q < 33; q++) {
        float t = acc[q];
        t += __shfl_xor(t, 1);
        t += __shfl_xor(t, 2);
        t += __shfl_xor(t, 4);
        acc[q] = t;
    }
    if (s == 0) {
        float* dst = JstP + (c * 24 + j) * 33;
#pragma unroll
        for (int q = 0; q < 33; q++) dst[q] = acc[q];
    }
}

// ---------------------------------------------------------------------------
// K1: reduce JstP + rodrigues + chain.  grid 16 x 256 thr; 16 batches/block,
// 16 lanes/batch (e<12 compute one element of the 3x4 chain result).
// ---------------------------------------------------------------------------
#define RES_STRIDE 292   // 288 + 4 pad: batches land on distinct banks
__global__ __launch_bounds__(256) void k_chain(const float* __restrict__ beta,
                                               const float* __restrict__ theta,
                                               const float* __restrict__ JstP,
                                               float* __restrict__ coefG,
                                               float* __restrict__ Aout)
{
    __shared__ float JstL[792];
    __shared__ float JL[16 * 72];              // [bl][j*3+d]
    __shared__ float resL[16 * RES_STRIDE];    // [bl][j*12+e]
    const int tid = threadIdx.x;
    const int bl = tid >> 4;                   // 0..15 batch-local
    const int e  = tid & 15;                   // 0..15 (12 active for matmul)
    const int b  = blockIdx.x * 16 + bl;
    const int m  = e >> 2, n = e & 3;

    for (int i = tid; i < 792; i += 256) {
        float s = 0.f;
#pragma unroll
        for (int c = 0; c < NCH_; c++) s += JstP[c * 792 + i];
        JstL[i] = s;
    }
    __syncthreads();

    // JL = J_template + beta . J_shape   (1152 items)
    for (int idx = tid; idx < 1152; idx += 256) {
        int bb = idx / 72, rem = idx % 72;     // rem = j*3+d
        int jj = rem / 3, d = rem % 3;
        const float* bp = beta + (size_t)(blockIdx.x * 16 + bb) * 10;
        float s = JstL[jj * 33 + d];
#pragma unroll
        for (int k = 0; k < 10; k++) s += bp[k] * JstL[jj * 33 + 3 + k * 3 + d];
        JL[bb * 72 + rem] = s;
    }
    // coefG beta rows (160 items)
    for (int idx = tid; idx < 160; idx += 256) {
        int bb = idx & 15, k = idx >> 4;
        int gb = blockIdx.x * 16 + bb;
        coefG[k * 256 + gb] = beta[(size_t)gb * 10 + k];
    }
    __syncthreads();

    const int par[24] = {0,0,0,0,1,2,3,4,5,6,7,8,9,9,9,12,13,14,16,17,18,19,20,21};

    for (int j = 0; j < 24; j++) {
        // rodrigues (computed redundantly per lane)
        float t0 = theta[(size_t)b * 72 + 3 * j + 0];
        float t1 = theta[(size_t)b * 72 + 3 * j + 1];
        float t2 = theta[(size_t)b * 72 + 3 * j + 2];
        float e0 = t0 + 1e-8f, e1 = t1 + 1e-8f, e2 = t2 + 1e-8f;
        float ang = sqrtf(e0 * e0 + e1 * e1 + e2 * e2);
        float inva = 1.0f / ang;
        float r0 = t0 * inva, r1 = t1 * inva, r2 = t2 * inva;
        float h = 0.5f * ang;
        float qw = cosf(h), sh = sinf(h);
        float qx = sh * r0, qy = sh * r1, qz = sh * r2;
        float inq = 1.0f / sqrtf(qw * qw + qx * qx + qy * qy + qz * qz);
        qw *= inq; qx *= inq; qy *= inq; qz *= inq;
        float R[9];
        R[0] = 1.f - 2.f * (qy * qy + qz * qz);
        R[1] = 2.f * (qx * qy - qw * qz);
        R[2] = 2.f * (qx * qz + qw * qy);
        R[3] = 2.f * (qx * qy + qw * qz);
        R[4] = 1.f - 2.f * (qx * qx + qz * qz);
        R[5] = 2.f * (qy * qz - qw * qx);
        R[6] = 2.f * (qx * qz - qw * qy);
        R[7] = 2.f * (qy * qz + qw * qx);
        R[8] = 1.f - 2.f * (qx * qx + qy * qy);

        if (j == 0) {
            if (e < 12) {
                float val;
                if (n < 3) val = R[m * 3 + n] * ((n == 0) ? 1.f : -1.f);
                else       val = JL[bl * 72 + 0 * 3 + m];
                resL[bl * RES_STRIDE + 0 * 12 + e] = val;
            }
        } else {
            if (e < 9)
                coefG[(10 + (j - 1) * 9 + e) * 256 + b] =
                    R[e] - ((e == 0 || e == 4 || e == 8) ? 1.f : 0.f);
            const int p = par[j];
            if (e < 12) {
                const float* pr = resL + bl * RES_STRIDE + p * 12 + m * 4;
                float pm0 = pr[0], pm1 = pr[1], pm2 = pr[2], pm3 = pr[3];
                float val;
                if (n < 3) {
                    val = pm0 * R[n] + pm1 * R[3 + n] + pm2 * R[6 + n];
                } else {
                    float tx = JL[bl * 72 + j * 3 + 0] - JL[bl * 72 + p * 3 + 0];
                    float ty = JL[bl * 72 + j * 3 + 1] - JL[bl * 72 + p * 3 + 1];
                    float tz = JL[bl * 72 + j * 3 + 2] - JL[bl * 72 + p * 3 + 2];
                    val = pm0 * tx + pm1 * ty + pm2 * tz + pm3;
                }
                resL[bl * RES_STRIDE + j * 12 + e] = val;
            }
        }
        __syncthreads();
    }

    // A epilogue: A[m][n<3] = res[m][n]; A[m][3] = res[m][3] - res[m][:3].J
    if (e < 12) {
        for (int j = 0; j < 24; j++) {
            const float* rr = resL + bl * RES_STRIDE + j * 12 + m * 4;
            float val;
            if (n < 3) {
                val = rr[n];
            } else {
                float Jx = JL[bl * 72 + j * 3 + 0];
                float Jy = JL[bl * 72 + j * 3 + 1];
                float Jz = JL[bl * 72 + j * 3 + 2];
                val = rr[3] - (rr[0] * Jx + rr[1] * Jy + rr[2] * Jz);
            }
            Aout[(size_t)(b * 24 + j) * 12 + e] = val;
        }
    }
}

// ---------------------------------------------------------------------------
// K2: v_posed GEMM, batch-stationary (sd/pd read once device-wide).
// ---------------------------------------------------------------------------
__global__ __launch_bounds__(256) void k_vposed(const float* __restrict__ cg,
                                                const float* __restrict__ vt,
                                                const float* __restrict__ sd,
                                                const float* __restrict__ pd,
                                                float* __restrict__ vp)
{
    __shared__ __align__(16) float tile[64 * 32];
    const int tid  = threadIdx.x;
    const int cbase = blockIdx.x * 32;
    const bool tail = (cbase + 32 > V3_);
    const int b0  = (tid & 63) * 4;
    const int cg8 = tid >> 6;

    float acc[4][8];
#pragma unroll
    for (int i = 0; i < 4; i++)
#pragma unroll
        for (int j = 0; j < 8; j++) acc[i][j] = 0.f;

    for (int kb = 0; kb < NK_; kb += 64) {
        const int rows = (NK_ - kb < 64) ? (NK_ - kb) : 64;
        __syncthreads();
#pragma unroll
        for (int i = 0; i < 4; i++) {
            int s = tid + 256 * i;
            int r = s >> 4, c2 = (s & 15) * 2;
            if (r < rows) {
                int gr = kb + r;
                const float* src = ((gr < NB_) ? (sd + (size_t)gr * V3_)
                                               : (pd + (size_t)(gr - NB_) * V3_))
                                   + cbase + c2;
                float2 vv;
                if (!tail) {
                    vv = *(const float2*)src;
                } else {
                    vv.x = (cbase + c2     < V3_) ? src[0] : 0.f;
                    vv.y = (cbase + c2 + 1 < V3_) ? src[1] : 0.f;
                }
                *(float2*)(tile + r * 32 + c2) = vv;
            }
        }
        __syncthreads();
#pragma unroll 8
        for (int u = 0; u < rows; u++) {
            const float4 c4 = *(const float4*)(cg + (size_t)(kb + u) * 256 + b0);
            const float* rv = tile + u * 32 + cg8 * 8;
            const float4 vA = *(const float4*)(rv);
            const float4 vB = *(const float4*)(rv + 4);
            float ci[4] = {c4.x, c4.y, c4.z, c4.w};
            float vj[8] = {vA.x, vA.y, vA.z, vA.w, vB.x, vB.y, vB.z, vB.w};
#pragma unroll
            for (int i = 0; i < 4; i++)
#pragma unroll
                for (int j = 0; j < 8; j++) acc[i][j] += ci[i] * vj[j];
        }
    }

    const int col0 = cbase + cg8 * 8;
    if (!tail) {
        const float4 tA = *(const float4*)(vt + col0);
        const float4 tB = *(const float4*)(vt + col0 + 4);
        float tv[8] = {tA.x, tA.y, tA.z, tA.w, tB.x, tB.y, tB.z, tB.w};
#pragma unroll
        for (int i = 0; i < 4; i++) {
            float* o = vp + (size_t)(b0 + i) * V3_ + col0;
#pragma unroll
            for (int q = 0; q < 4; q++) {
                float2 st = {acc[i][2*q] + tv[2*q], acc[i][2*q+1] + tv[2*q+1]};
                *(float2*)(o + 2*q) = st;
            }
        }
    } else {
        float tv[8];
#pragma unroll
        for (int j = 0; j < 8; j++) tv[j] = (col0 + j < V3_) ? vt[col0 + j] : 0.f;
#pragma unroll
        for (int i = 0; i < 4; i++) {
            float* o = vp + (size_t)(b0 + i) * V3_ + col0;
#pragma unroll
            for (int j = 0; j < 8; j++)
                if (col0 + j < V3_) o[j] = acc[i][j] + tv[j];
        }
    }
}

// ---------------------------------------------------------------------------
// K3: skinning, in place.  weights batch-broadcast -> slice [0].
// ---------------------------------------------------------------------------
__global__ __launch_bounds__(256) void k_skin(const float* __restrict__ w0,
                                              const float* __restrict__ A,
                                              float* __restrict__ verts)
{
    __shared__ __align__(16) float AL[288];
    const int tid = threadIdx.x;
    const int b = blockIdx.y;
    for (int i = tid; i < 288; i += 256) AL[i] = A[(size_t)b * 288 + i];
    __syncthreads();

#pragma unroll
    for (int rep = 0; rep < 2; rep++) {
        int v = blockIdx.x * 512 + rep * 256 + tid;
        if (v >= V_) continue;
        float wr[24];
        const float4* wp = (const float4*)(w0 + (size_t)v * 24);
#pragma unroll
        for (int q = 0; q < 6; q++) {
            float4 f = wp[q];
            wr[q * 4 + 0] = f.x; wr[q * 4 + 1] = f.y;
            wr[q * 4 + 2] = f.z; wr[q * 4 + 3] = f.w;
        }
        float T[12];
#pragma unroll
        for (int e = 0; e < 12; e++) T[e] = 0.f;
#pragma unroll
        for (int j = 0; j < 24; j++) {
            const float4* a4 = (const float4*)(AL + j * 12);
            float4 a0 = a4[0], a1 = a4[1], a2 = a4[2];
            float wj = wr[j];
            T[0] += wj * a0.x; T[1] += wj * a0.y; T[2]  += wj * a0.z; T[3]  += wj * a0.w;
            T[4] += wj * a1.x; T[5] += wj * a1.y; T[6]  += wj * a1.z; T[7]  += wj * a1.w;
            T[8] += wj * a2.x; T[9] += wj * a2.y; T[10] += wj * a2.z; T[11] += wj * a2.w;
        }
        float* pv = verts + (size_t)b * V3_ + (size_t)v * 3;
        float p0 = pv[0], p1 = pv[1], p2 = pv[2];
        pv[0] = T[0] * p0 + T[1] * p1 + T[2]  * p2 + T[3];
        pv[1] = T[4] * p0 + T[5] * p1 + T[6]  * p2 + T[7];
        pv[2] = T[8] * p0 + T[9] * p1 + T[10] * p2 + T[11];
    }
}

// ---------------------------------------------------------------------------
// K4: joint regression partials.  grid (64 b-tiles, 4 jr-tiles of 11, 4 v).
// ---------------------------------------------------------------------------
__global__ __launch_bounds__(256) void k_joints(const float* __restrict__ jreg,
                                                const float* __restrict__ verts,
                                                float* __restrict__ jp)
{
    const int tid = threadIdx.x;
    const int b0 = blockIdx.x * 4;
    const int jr0 = blockIdx.y * 11;
    const int z = blockIdx.z;
    const int v0 = z * 1723;
    const int v1 = (z == 3) ? V_ : v0 + 1723;

    float acc[132];
#pragma unroll
    for (int c = 0; c < 132; c++) acc[c] = 0.f;

    for (int v = v0 + tid; v < v1; v += 256) {
        float jr[11];
#pragma unroll
        for (int q = 0; q < 11; q++) {
            int j = jr0 + q;
            jr[q] = (j < NJR_) ? jreg[(size_t)j * V_ + v] : 0.f;
        }
#pragma unroll
        for (int i = 0; i < 4; i++) {
            const float* pv = verts + (size_t)(b0 + i) * V3_ + (size_t)v * 3;
            float p0 = pv[0], p1 = pv[1], p2 = pv[2];
#pragma unroll
            for (int q = 0; q < 11; q++) {
                acc[q * 12 + i * 3 + 0] += jr[q] * p0;
                acc[q * 12 + i * 3 + 1] += jr[q] * p1;
                acc[q * 12 + i * 3 + 2] += jr[q] * p2;
            }
        }
    }
#pragma unroll
    for (int c = 0; c < 132; c++) {
        float s = acc[c];
#pragma unroll
        for (int off = 32; off > 0; off >>= 1) s += __shfl_xor(s, off);
        acc[c] = s;
    }
    __shared__ float red[4][132];
    const int wv = tid >> 6, ln = tid & 63;
    if (ln == 0) {
#pragma unroll
        for (int c = 0; c < 132; c++) red[wv][c] = acc[c];
    }
    __syncthreads();
    if (tid < 132) {
        float s = red[0][tid] + red[1][tid] + red[2][tid] + red[3][tid];
        int q = tid / 12, rem = tid % 12, i2 = rem / 3, d = rem % 3;
        int j = jr0 + q;
        if (j < NJR_)
            jp[(size_t)z * JOUT_ + (b0 + i2) * NJ3_ + j * 3 + d] = s;
    }
}

// K5: sum the 4 partials into joints output
__global__ __launch_bounds__(256) void k_jfinal(const float* __restrict__ jp,
                                                float* __restrict__ joints)
{
    int i = blockIdx.x * 256 + threadIdx.x;
    if (i < JOUT_)
        joints[i] = jp[i] + jp[JOUT_ + i] + jp[2 * JOUT_ + i] + jp[3 * JOUT_ + i];
}

extern "C" void kernel_launch(void* const* d_in, const int* in_sizes, int n_in,
                              void* d_out, int out_size, void* d_ws, size_t ws_size,
                              hipStream_t stream)
{
    const float* beta  = (const float*)d_in[0];
    const float* theta = (const float*)d_in[1];
    const float* vtm   = (const float*)d_in[2];
    const float* sd    = (const float*)d_in[3];
    const float* pd    = (const float*)d_in[4];
    const float* JR    = (const float*)d_in[5];
    const float* jreg  = (const float*)d_in[6];
    const float* wts   = (const float*)d_in[7];  // batch-broadcast: slice [0]

    float* out = (float*)d_out;
    float* ws  = (float*)d_ws;
    float* JstP = ws + JSTP_OFF;
    float* cg   = ws + CG_OFF;
    float* A    = ws + A_OFF;
    float* jp   = ws + JP_OFF;
    float* verts  = out;
    float* joints = out + (size_t)B_ * V3_;

    hipLaunchKernelGGL(k_jst,    dim3(NCH_),     dim3(192), 0, stream, JR, vtm, sd, JstP);
    hipLaunchKernelGGL(k_chain,  dim3(16),       dim3(256), 0, stream, beta, theta, JstP, cg, A);
    hipLaunchKernelGGL(k_vposed, dim3(646),      dim3(256), 0, stream, cg, vtm, sd, pd, verts);
    hipLaunchKernelGGL(k_skin,   dim3(14, 256),  dim3(256), 0, stream, wts, A, verts);
    hipLaunchKernelGGL(k_joints, dim3(64, 4, 4), dim3(256), 0, stream, jreg, verts, jp);
    hipLaunchKernelGGL(k_jfinal, dim3(129),      dim3(256), 0, stream, jp, joints);
}